// Round 4
// baseline (484.518 us; speedup 1.0000x reference)
//
#include <hip/hip_runtime.h>
#include <hip/hip_bf16.h>
#include <stdint.h>

// Problem constants
#define NS 32          // samples
#define NA 512         // atoms
#define IND 64         // in_depth
#define OD 64          // out_depth
#define FL 12          // filter_length
#define KTOT (NA*FL)   // 6144 contraction length (k = n*12 + f)
#define WROW 66        // filters innermost dim (in_depth+2)

typedef __bf16 bf16x8 __attribute__((ext_vector_type(8)));
typedef float  f32x4  __attribute__((ext_vector_type(4)));

// ---------------------------------------------------------------------------
// Kernel 1: Gt[s][o][n*12+f] = sum_d node[s][n][d] * W[o][f][d]  (bf16)
// Change vs round 3: o is NO LONGER readfirstlane-uniform -> W reads go
// through pipelined VMEM (lanes share the address -> 1 cacheline/load,
// L1/L2-hit) instead of a serial SGPR-starved scalar-load chain.
// ---------------------------------------------------------------------------
__global__ __launch_bounds__(256, 4)
void k_prep(const float* __restrict__ node, const float* __restrict__ W,
            __bf16* __restrict__ gt) {
    const int bid = blockIdx.x;
    const int s  = bid >> 6;          // 0..31
    const int ac = (bid >> 3) & 7;    // 0..7  atom chunk
    const int og = bid & 7;           // 0..7  o-group (8 o each)
    const int a0 = ac << 6;
    const int tid = threadIdx.x;
    const int l  = tid & 63;

    __shared__ float nl[64][68];
    const f32x4* n4 = reinterpret_cast<const f32x4*>(node + ((size_t)s * NA + a0) * IND);
    #pragma unroll
    for (int it = 0; it < 4; ++it) {
        const int idx = tid + it * 256;
        const int row = idx >> 4, c4 = idx & 15;
        *reinterpret_cast<f32x4*>(&nl[row][c4 * 4]) = n4[idx];
    }
    __syncthreads();

    float nv[64];
    #pragma unroll
    for (int j = 0; j < 16; ++j)
        *reinterpret_cast<f32x4*>(&nv[4 * j]) =
            *reinterpret_cast<const f32x4*>(&nl[l][4 * j]);

    const int wv = tid >> 6;          // wave id 0..3 (kept divergent on purpose)

    #pragma unroll
    for (int oi = 0; oi < 2; ++oi) {
        const int o = og * 8 + wv * 2 + oi;
        const float* wb = W + (size_t)o * (FL * WROW);
        float acc[FL];
        #pragma unroll
        for (int f = 0; f < FL; ++f) {
            const float* wf = wb + f * WROW;
            float p0 = 0.f, p1 = 0.f, p2 = 0.f, p3 = 0.f;
            #pragma unroll
            for (int d = 0; d < 64; d += 4) {
                p0 += nv[d]     * wf[d];
                p1 += nv[d + 1] * wf[d + 1];
                p2 += nv[d + 2] * wf[d + 2];
                p3 += nv[d + 3] * wf[d + 3];
            }
            acc[f] = (p0 + p1) + (p2 + p3);
        }
        alignas(8) __bf16 ob[FL];
        #pragma unroll
        for (int f = 0; f < FL; ++f) ob[f] = (__bf16)acc[f];
        uint2* dst = reinterpret_cast<uint2*>(
            gt + ((size_t)s * OD + o) * KTOT + (size_t)(a0 + l) * FL);
        const uint2* src = reinterpret_cast<const uint2*>(ob);
        dst[0] = src[0]; dst[1] = src[1]; dst[2] = src[2];
    }
}

// ---------------------------------------------------------------------------
// Kernel 2: out[s][a][o] = bond-term (base value for k_main's atomicAdd).
// ---------------------------------------------------------------------------
__global__ __launch_bounds__(256)
void k_init(const float* __restrict__ bond, const float* __restrict__ W,
            float* __restrict__ out) {
    const int bid = blockIdx.x;
    const int tid = threadIdx.x;

    __shared__ float Wb[64][25];
    for (int i = tid; i < 64 * 24; i += 256) {
        const int o = i / 24, fc = i % 24;
        const int f = fc >> 1, c = fc & 1;
        Wb[o][fc] = W[(size_t)o * (FL * WROW) + f * WROW + IND + c];
    }
    __shared__ float bl[4][24];
    if (tid < 96) {
        const int a = tid / 24, fc = tid % 24;
        bl[a][fc] = bond[(size_t)bid * 4 * (FL * 2) + a * (FL * 2) + fc];
    }
    __syncthreads();

    const int aL = tid >> 6, o = tid & 63;
    float sum = 0.f;
    #pragma unroll
    for (int f = 0; f < FL; ++f)
        sum += bl[aL][2 * f] * Wb[o][2 * f] + bl[aL][2 * f + 1] * Wb[o][2 * f + 1];
    out[((size_t)bid * 4 + aL) * OD + o] = sum;
}

// ---------------------------------------------------------------------------
// Kernel 3: LDS-staged MFMA GEMM, pipelined. Per sample: C[512x64] += conn.Gt^T.
// vs round 3: (a) ONE raw s_barrier per K-step (double-buffer needs no more),
// (b) explicit "s_waitcnt lgkmcnt(0)" before the barrier (write visibility)
// instead of __syncthreads' full vmcnt(0) drain, (c) 2-deep register prefetch
// (loads for step t+2 issued at step t) -> hazard wait at the LDS write is a
// counted vmcnt(6), prefetch loads stay in flight across barriers.
// ---------------------------------------------------------------------------
struct PF { f32x4 a0, a1, a2, a3; uint4 b0, b1; };

__device__ __forceinline__ PF pf_load(const float* ap, const __bf16* bp) {
    PF p;
    p.a0 = *reinterpret_cast<const f32x4*>(ap);
    p.a1 = *reinterpret_cast<const f32x4*>(ap + 4);
    p.a2 = *reinterpret_cast<const f32x4*>(ap + 8);
    p.a3 = *reinterpret_cast<const f32x4*>(ap + 12);
    p.b0 = *reinterpret_cast<const uint4*>(bp);
    p.b1 = *reinterpret_cast<const uint4*>(bp + 8);
    return p;
}

__device__ __forceinline__ void pf_stage(unsigned char* Ab, unsigned char* Bb,
                                         const PF& p, int woff0, int woff1) {
    bf16x8 wlo, whi;
    wlo[0] = (__bf16)p.a0.x; wlo[1] = (__bf16)p.a0.y;
    wlo[2] = (__bf16)p.a0.z; wlo[3] = (__bf16)p.a0.w;
    wlo[4] = (__bf16)p.a1.x; wlo[5] = (__bf16)p.a1.y;
    wlo[6] = (__bf16)p.a1.z; wlo[7] = (__bf16)p.a1.w;
    whi[0] = (__bf16)p.a2.x; whi[1] = (__bf16)p.a2.y;
    whi[2] = (__bf16)p.a2.z; whi[3] = (__bf16)p.a2.w;
    whi[4] = (__bf16)p.a3.x; whi[5] = (__bf16)p.a3.y;
    whi[6] = (__bf16)p.a3.z; whi[7] = (__bf16)p.a3.w;
    *reinterpret_cast<bf16x8*>(Ab + woff0) = wlo;
    *reinterpret_cast<bf16x8*>(Ab + woff1) = whi;
    *reinterpret_cast<uint4*>(Bb + woff0) = p.b0;
    *reinterpret_cast<uint4*>(Bb + woff1) = p.b1;
}

__device__ __forceinline__ void mfma_phase(const unsigned char* Ab, const unsigned char* Bb,
                                           int rowA0, int rowB0, int lg, int rsw,
                                           f32x4& c00, f32x4& c01, f32x4& c10, f32x4& c11) {
    #pragma unroll
    for (int ks = 0; ks < 2; ++ks) {
        const int koff = (ks * 64 + lg * 16) ^ rsw;
        const bf16x8 am0 = *reinterpret_cast<const bf16x8*>(Ab + rowA0 + koff);
        const bf16x8 am1 = *reinterpret_cast<const bf16x8*>(Ab + rowA0 + 2048 + koff);
        const bf16x8 bn0 = *reinterpret_cast<const bf16x8*>(Bb + rowB0 + koff);
        const bf16x8 bn1 = *reinterpret_cast<const bf16x8*>(Bb + rowB0 + 2048 + koff);
        c00 = __builtin_amdgcn_mfma_f32_16x16x32_bf16(am0, bn0, c00, 0, 0, 0);
        c01 = __builtin_amdgcn_mfma_f32_16x16x32_bf16(am0, bn1, c01, 0, 0, 0);
        c10 = __builtin_amdgcn_mfma_f32_16x16x32_bf16(am1, bn0, c10, 0, 0, 0);
        c11 = __builtin_amdgcn_mfma_f32_16x16x32_bf16(am1, bn1, c11, 0, 0, 0);
    }
}

__global__ __launch_bounds__(256, 4)
void k_main(const float* __restrict__ conn, const __bf16* __restrict__ gt,
            float* __restrict__ out) {
    const int bid = blockIdx.x;
    const int s  = bid & 31;
    const int x  = bid >> 5;
    const int at = x >> 2;            // 0..7
    const int kq = x & 3;             // 0..3
    const int a0 = at << 6;
    const int k00 = kq * (KTOT / 4);  // 1536-elem K slice, 24 steps of 64
    const int tid = threadIdx.x;
    const int w  = tid >> 6, l = tid & 63;
    const int lr = l & 15, lg = l >> 4;
    const int m0 = (w >> 1) << 5;
    const int n0 = (w & 1) << 5;

    __shared__ __align__(16) unsigned char Al0[8192];
    __shared__ __align__(16) unsigned char Al1[8192];
    __shared__ __align__(16) unsigned char Bl0[8192];
    __shared__ __align__(16) unsigned char Bl1[8192];

    const int srow = tid >> 2;
    const int scol = tid & 3;
    const float*  aG = conn + ((size_t)s * NA + a0 + srow) * KTOT + k00 + scol * 16;
    const __bf16* bG = gt   + ((size_t)s * OD + srow)      * KTOT + k00 + scol * 16;
    const int wsw   = (srow & 7) << 4;
    const int woff0 = srow * 128 + ((scol * 32) ^ wsw);
    const int woff1 = srow * 128 + ((scol * 32 + 16) ^ wsw);

    f32x4 acc00 = {0.f,0.f,0.f,0.f}, acc01 = {0.f,0.f,0.f,0.f};
    f32x4 acc10 = {0.f,0.f,0.f,0.f}, acc11 = {0.f,0.f,0.f,0.f};

    const int rsw = (lr & 7) << 4;
    const int rowA0 = (m0 + lr) * 128;
    const int rowB0 = (n0 + lr) * 128;

    PF P0 = pf_load(aG, bG);
    PF P1 = pf_load(aG + 64, bG + 64);

    #pragma unroll 1
    for (int t = 0; t < 24; t += 2) {
        // ---- even step: buffer 0 ----
        pf_stage(Al0, Bl0, P0, woff0, woff1);          // waits vmcnt(6): P1 in flight
        if (t + 2 < 24) P0 = pf_load(aG + (t + 2) * 64, bG + (t + 2) * 64);
        asm volatile("s_waitcnt lgkmcnt(0)" ::: "memory");
        __builtin_amdgcn_s_barrier();
        mfma_phase(Al0, Bl0, rowA0, rowB0, lg, rsw, acc00, acc01, acc10, acc11);

        // ---- odd step: buffer 1 ----
        pf_stage(Al1, Bl1, P1, woff0, woff1);
        if (t + 3 < 24) P1 = pf_load(aG + (t + 3) * 64, bG + (t + 3) * 64);
        asm volatile("s_waitcnt lgkmcnt(0)" ::: "memory");
        __builtin_amdgcn_s_barrier();
        mfma_phase(Al1, Bl1, rowA0, rowB0, lg, rsw, acc00, acc01, acc10, acc11);
    }

    // epilogue: atomic accumulate partials. D: col=lane&15, row=4*(lane>>4)+r
    float* ob = out + ((size_t)s * NA + a0 + m0 + lg * 4) * OD + n0 + lr;
    #pragma unroll
    for (int r = 0; r < 4; ++r) {
        atomicAdd(ob + (size_t)(r) * OD,            acc00[r]);
        atomicAdd(ob + (size_t)(r) * OD + 16,       acc01[r]);
        atomicAdd(ob + (size_t)(16 + r) * OD,       acc10[r]);
        atomicAdd(ob + (size_t)(16 + r) * OD + 16,  acc11[r]);
    }
}

extern "C" void kernel_launch(void* const* d_in, const int* in_sizes, int n_in,
                              void* d_out, int out_size, void* d_ws, size_t ws_size,
                              hipStream_t stream) {
    const float* node = (const float*)d_in[0];
    const float* conn = (const float*)d_in[1];
    const float* bond = (const float*)d_in[2];
    const float* W    = (const float*)d_in[3];
    float* out = (float*)d_out;
    __bf16* gt = (__bf16*)d_ws;    // 32*64*6144 bf16 = 25.2 MB

    k_prep<<<dim3(NS * 64), dim3(256), 0, stream>>>(node, W, gt);
    k_init<<<dim3(NS * NA / 4), dim3(256), 0, stream>>>(bond, W, out);
    k_main<<<dim3(NS * 32), dim3(256), 0, stream>>>(conn, gt, out);
}

// Round 5
// 200.028 us; speedup vs baseline: 2.4222x; 2.4222x over previous
//
#include <hip/hip_runtime.h>
#include <hip/hip_bf16.h>
#include <stdint.h>

// Problem constants
#define NS 32          // samples
#define NA 512         // atoms
#define IND 64         // in_depth
#define OD 64          // out_depth
#define FL 12          // filter_length
#define KTOT (NA*FL)   // 6144 contraction length (k = n*12 + f)
#define WROW 66        // filters innermost dim (in_depth+2)

typedef __bf16 bf16x8 __attribute__((ext_vector_type(8)));
typedef float  f32x4  __attribute__((ext_vector_type(4)));

// ---------------------------------------------------------------------------
// Kernel 1: Gt[s][o][n*12+f] = sum_d node[s][n][d] * W[o][f][d]  (bf16)
// EXACT round-3 version (fast): o is wave-uniform via readfirstlane -> W goes
// through the scalar path (s_load, W values folded as SGPR operands into
// v_fma, near-zero VGPR cost -> no spill). Do NOT "fix" this.
// ---------------------------------------------------------------------------
__global__ __launch_bounds__(256)
void k_prep(const float* __restrict__ node, const float* __restrict__ W,
            __bf16* __restrict__ gt) {
    const int bid = blockIdx.x;
    const int s  = bid >> 6;          // 0..31
    const int ac = (bid >> 3) & 7;    // 0..7  atom chunk
    const int og = bid & 7;           // 0..7  o-group (8 o each)
    const int a0 = ac << 6;
    const int tid = threadIdx.x;
    const int l  = tid & 63;

    __shared__ float nl[64][68];
    const f32x4* n4 = reinterpret_cast<const f32x4*>(node + ((size_t)s * NA + a0) * IND);
    #pragma unroll
    for (int it = 0; it < 4; ++it) {
        const int idx = tid + it * 256;
        const int row = idx >> 4, c4 = idx & 15;
        *reinterpret_cast<f32x4*>(&nl[row][c4 * 4]) = n4[idx];
    }
    __syncthreads();

    float nv[64];
    #pragma unroll
    for (int j = 0; j < 16; ++j)
        *reinterpret_cast<f32x4*>(&nv[4 * j]) =
            *reinterpret_cast<const f32x4*>(&nl[l][4 * j]);

    const int wv = __builtin_amdgcn_readfirstlane(tid >> 6);   // wave id 0..3

    for (int oi = 0; oi < 2; ++oi) {                  // o wave-uniform
        const int o = og * 8 + wv * 2 + oi;
        const float* wb = W + (size_t)o * (FL * WROW);
        float acc[FL];
        #pragma unroll
        for (int f = 0; f < FL; ++f) {
            const float* wf = wb + f * WROW;
            float p0 = 0.f, p1 = 0.f, p2 = 0.f, p3 = 0.f;
            #pragma unroll
            for (int d = 0; d < 64; d += 4) {
                p0 += nv[d]     * wf[d];
                p1 += nv[d + 1] * wf[d + 1];
                p2 += nv[d + 2] * wf[d + 2];
                p3 += nv[d + 3] * wf[d + 3];
            }
            acc[f] = (p0 + p1) + (p2 + p3);
        }
        alignas(8) __bf16 ob[FL];
        #pragma unroll
        for (int f = 0; f < FL; ++f) ob[f] = (__bf16)acc[f];
        uint2* dst = reinterpret_cast<uint2*>(
            gt + ((size_t)s * OD + o) * KTOT + (size_t)(a0 + l) * FL);
        const uint2* src = reinterpret_cast<const uint2*>(ob);
        dst[0] = src[0]; dst[1] = src[1]; dst[2] = src[2];
    }
}

// ---------------------------------------------------------------------------
// Kernel 2: out[s][a][o] = bond-term (base value for k_main's atomicAdd).
// ---------------------------------------------------------------------------
__global__ __launch_bounds__(256)
void k_init(const float* __restrict__ bond, const float* __restrict__ W,
            float* __restrict__ out) {
    const int bid = blockIdx.x;
    const int tid = threadIdx.x;

    __shared__ float Wb[64][25];
    for (int i = tid; i < 64 * 24; i += 256) {
        const int o = i / 24, fc = i % 24;
        const int f = fc >> 1, c = fc & 1;
        Wb[o][fc] = W[(size_t)o * (FL * WROW) + f * WROW + IND + c];
    }
    __shared__ float bl[4][24];
    if (tid < 96) {
        const int a = tid / 24, fc = tid % 24;
        bl[a][fc] = bond[(size_t)bid * 4 * (FL * 2) + a * (FL * 2) + fc];
    }
    __syncthreads();

    const int aL = tid >> 6, o = tid & 63;
    float sum = 0.f;
    #pragma unroll
    for (int f = 0; f < FL; ++f)
        sum += bl[aL][2 * f] * Wb[o][2 * f] + bl[aL][2 * f + 1] * Wb[o][2 * f + 1];
    out[((size_t)bid * 4 + aL) * OD + o] = sum;
}

// ---------------------------------------------------------------------------
// Kernel 3 (round-4 version, validated ~87us): pipelined LDS-staged MFMA GEMM.
// One raw s_barrier per K-step, explicit lgkmcnt(0) (no vmcnt drain), 2-deep
// register prefetch -> counted vmcnt waits, loads in flight across barriers.
// ---------------------------------------------------------------------------
struct PF { f32x4 a0, a1, a2, a3; uint4 b0, b1; };

__device__ __forceinline__ PF pf_load(const float* ap, const __bf16* bp) {
    PF p;
    p.a0 = *reinterpret_cast<const f32x4*>(ap);
    p.a1 = *reinterpret_cast<const f32x4*>(ap + 4);
    p.a2 = *reinterpret_cast<const f32x4*>(ap + 8);
    p.a3 = *reinterpret_cast<const f32x4*>(ap + 12);
    p.b0 = *reinterpret_cast<const uint4*>(bp);
    p.b1 = *reinterpret_cast<const uint4*>(bp + 8);
    return p;
}

__device__ __forceinline__ void pf_stage(unsigned char* Ab, unsigned char* Bb,
                                         const PF& p, int woff0, int woff1) {
    bf16x8 wlo, whi;
    wlo[0] = (__bf16)p.a0.x; wlo[1] = (__bf16)p.a0.y;
    wlo[2] = (__bf16)p.a0.z; wlo[3] = (__bf16)p.a0.w;
    wlo[4] = (__bf16)p.a1.x; wlo[5] = (__bf16)p.a1.y;
    wlo[6] = (__bf16)p.a1.z; wlo[7] = (__bf16)p.a1.w;
    whi[0] = (__bf16)p.a2.x; whi[1] = (__bf16)p.a2.y;
    whi[2] = (__bf16)p.a2.z; whi[3] = (__bf16)p.a2.w;
    whi[4] = (__bf16)p.a3.x; whi[5] = (__bf16)p.a3.y;
    whi[6] = (__bf16)p.a3.z; whi[7] = (__bf16)p.a3.w;
    *reinterpret_cast<bf16x8*>(Ab + woff0) = wlo;
    *reinterpret_cast<bf16x8*>(Ab + woff1) = whi;
    *reinterpret_cast<uint4*>(Bb + woff0) = p.b0;
    *reinterpret_cast<uint4*>(Bb + woff1) = p.b1;
}

__device__ __forceinline__ void mfma_phase(const unsigned char* Ab, const unsigned char* Bb,
                                           int rowA0, int rowB0, int lg, int rsw,
                                           f32x4& c00, f32x4& c01, f32x4& c10, f32x4& c11) {
    #pragma unroll
    for (int ks = 0; ks < 2; ++ks) {
        const int koff = (ks * 64 + lg * 16) ^ rsw;
        const bf16x8 am0 = *reinterpret_cast<const bf16x8*>(Ab + rowA0 + koff);
        const bf16x8 am1 = *reinterpret_cast<const bf16x8*>(Ab + rowA0 + 2048 + koff);
        const bf16x8 bn0 = *reinterpret_cast<const bf16x8*>(Bb + rowB0 + koff);
        const bf16x8 bn1 = *reinterpret_cast<const bf16x8*>(Bb + rowB0 + 2048 + koff);
        c00 = __builtin_amdgcn_mfma_f32_16x16x32_bf16(am0, bn0, c00, 0, 0, 0);
        c01 = __builtin_amdgcn_mfma_f32_16x16x32_bf16(am0, bn1, c01, 0, 0, 0);
        c10 = __builtin_amdgcn_mfma_f32_16x16x32_bf16(am1, bn0, c10, 0, 0, 0);
        c11 = __builtin_amdgcn_mfma_f32_16x16x32_bf16(am1, bn1, c11, 0, 0, 0);
    }
}

__global__ __launch_bounds__(256, 4)
void k_main(const float* __restrict__ conn, const __bf16* __restrict__ gt,
            float* __restrict__ out) {
    const int bid = blockIdx.x;
    const int s  = bid & 31;
    const int x  = bid >> 5;
    const int at = x >> 2;            // 0..7
    const int kq = x & 3;             // 0..3
    const int a0 = at << 6;
    const int k00 = kq * (KTOT / 4);  // 1536-elem K slice, 24 steps of 64
    const int tid = threadIdx.x;
    const int w  = tid >> 6, l = tid & 63;
    const int lr = l & 15, lg = l >> 4;
    const int m0 = (w >> 1) << 5;
    const int n0 = (w & 1) << 5;

    __shared__ __align__(16) unsigned char Al0[8192];
    __shared__ __align__(16) unsigned char Al1[8192];
    __shared__ __align__(16) unsigned char Bl0[8192];
    __shared__ __align__(16) unsigned char Bl1[8192];

    const int srow = tid >> 2;
    const int scol = tid & 3;
    const float*  aG = conn + ((size_t)s * NA + a0 + srow) * KTOT + k00 + scol * 16;
    const __bf16* bG = gt   + ((size_t)s * OD + srow)      * KTOT + k00 + scol * 16;
    const int wsw   = (srow & 7) << 4;
    const int woff0 = srow * 128 + ((scol * 32) ^ wsw);
    const int woff1 = srow * 128 + ((scol * 32 + 16) ^ wsw);

    f32x4 acc00 = {0.f,0.f,0.f,0.f}, acc01 = {0.f,0.f,0.f,0.f};
    f32x4 acc10 = {0.f,0.f,0.f,0.f}, acc11 = {0.f,0.f,0.f,0.f};

    const int rsw = (lr & 7) << 4;
    const int rowA0 = (m0 + lr) * 128;
    const int rowB0 = (n0 + lr) * 128;

    PF P0 = pf_load(aG, bG);
    PF P1 = pf_load(aG + 64, bG + 64);

    #pragma unroll 1
    for (int t = 0; t < 24; t += 2) {
        // ---- even step: buffer 0 ----
        pf_stage(Al0, Bl0, P0, woff0, woff1);          // waits vmcnt(6): P1 in flight
        if (t + 2 < 24) P0 = pf_load(aG + (t + 2) * 64, bG + (t + 2) * 64);
        asm volatile("s_waitcnt lgkmcnt(0)" ::: "memory");
        __builtin_amdgcn_s_barrier();
        mfma_phase(Al0, Bl0, rowA0, rowB0, lg, rsw, acc00, acc01, acc10, acc11);

        // ---- odd step: buffer 1 ----
        pf_stage(Al1, Bl1, P1, woff0, woff1);
        if (t + 3 < 24) P1 = pf_load(aG + (t + 3) * 64, bG + (t + 3) * 64);
        asm volatile("s_waitcnt lgkmcnt(0)" ::: "memory");
        __builtin_amdgcn_s_barrier();
        mfma_phase(Al1, Bl1, rowA0, rowB0, lg, rsw, acc00, acc01, acc10, acc11);
    }

    // epilogue: atomic accumulate partials. D: col=lane&15, row=4*(lane>>4)+r
    float* ob = out + ((size_t)s * NA + a0 + m0 + lg * 4) * OD + n0 + lr;
    #pragma unroll
    for (int r = 0; r < 4; ++r) {
        atomicAdd(ob + (size_t)(r) * OD,            acc00[r]);
        atomicAdd(ob + (size_t)(r) * OD + 16,       acc01[r]);
        atomicAdd(ob + (size_t)(16 + r) * OD,       acc10[r]);
        atomicAdd(ob + (size_t)(16 + r) * OD + 16,  acc11[r]);
    }
}

extern "C" void kernel_launch(void* const* d_in, const int* in_sizes, int n_in,
                              void* d_out, int out_size, void* d_ws, size_t ws_size,
                              hipStream_t stream) {
    const float* node = (const float*)d_in[0];
    const float* conn = (const float*)d_in[1];
    const float* bond = (const float*)d_in[2];
    const float* W    = (const float*)d_in[3];
    float* out = (float*)d_out;
    __bf16* gt = (__bf16*)d_ws;    // 32*64*6144 bf16 = 25.2 MB

    k_prep<<<dim3(NS * 64), dim3(256), 0, stream>>>(node, W, gt);
    k_init<<<dim3(NS * NA / 4), dim3(256), 0, stream>>>(bond, W, out);
    k_main<<<dim3(NS * 32), dim3(256), 0, stream>>>(conn, gt, out);
}

// Round 6
// 131.003 us; speedup vs baseline: 3.6985x; 1.5269x over previous
//
#include <hip/hip_runtime.h>
#include <hip/hip_bf16.h>
#include <stdint.h>

// Problem constants
#define NS 32          // samples
#define NA 512         // atoms
#define IND 64         // in_depth
#define OD 64          // out_depth
#define FL 12          // filter_length
#define KTOT (NA*FL)   // 6144 contraction length (k = n*12 + f)
#define WROW 66        // filters innermost dim (in_depth+2)

typedef __bf16 bf16x8 __attribute__((ext_vector_type(8)));
typedef float  f32x4  __attribute__((ext_vector_type(4)));
typedef float  f32x4a __attribute__((ext_vector_type(4), aligned(4)));  // 4B-aligned vec load

// ---------------------------------------------------------------------------
// Kernel 1 (v3, MFMA): Gt[s][o][n*12+f] = sum_d node[s][n][d]*W[o][f][d] (bf16)
// Block = (s, n-half 256, o-group 16). Grid 256 = 1 block/CU, 4 waves.
// - node half staged f32->bf16 into LDS [256 n][64 d], XOR-swizzled
//   (byte ^= (n&7)<<4) so B-fragment ds_read_b128 is conflict-free.
// - Each wave preloads its 24 A-fragments (W rows for its 16 o's, 12 f x 2
//   k-halves) once; o=lane&15, k=8*(lane>>4)+j (layout validated by k_main).
// - Per n-tile: 24 MFMA (12 f x 2), D[row=o][col=n], then per-wave LDS
//   transpose buffer (XOR-swizzled) -> contiguous 384B global runs per o-row.
// ---------------------------------------------------------------------------
__global__ __launch_bounds__(256, 1)
void k_prep(const float* __restrict__ node, const float* __restrict__ W,
            __bf16* __restrict__ gt) {
    const int bid = blockIdx.x;          // 256 blocks
    const int s  = bid >> 3;             // 0..31
    const int nh = (bid >> 2) & 1;       // 0..1
    const int og = bid & 3;              // 0..3
    const int o0 = og * 16;
    const int nbase = nh * 256;
    const int tid = threadIdx.x;
    const int wv = tid >> 6, l = tid & 63;
    const int lr = l & 15, lg = l >> 4;

    __shared__ __align__(16) unsigned char NodeL[256 * 128];   // [n][d] bf16, swizzled
    __shared__ __align__(16) unsigned char Tr[4][6144];        // per-wave transpose buf

    // ---- A-fragment preload (independent of LDS; overlaps staging) ----
    bf16x8 afr[FL][2];
    {
        const float* wrow = W + (size_t)(o0 + lr) * (FL * WROW);
        #pragma unroll
        for (int f = 0; f < FL; ++f) {
            #pragma unroll
            for (int kk = 0; kk < 2; ++kk) {
                const float* p = wrow + f * WROW + kk * 32 + lg * 8;
                const f32x4a u0 = *reinterpret_cast<const f32x4a*>(p);
                const f32x4a u1 = *reinterpret_cast<const f32x4a*>(p + 4);
                bf16x8 a;
                a[0] = (__bf16)u0.x; a[1] = (__bf16)u0.y;
                a[2] = (__bf16)u0.z; a[3] = (__bf16)u0.w;
                a[4] = (__bf16)u1.x; a[5] = (__bf16)u1.y;
                a[6] = (__bf16)u1.z; a[7] = (__bf16)u1.w;
                afr[f][kk] = a;
            }
        }
    }

    // ---- stage node[s][nbase..+256][0:64] -> bf16 LDS, swizzled, coalesced ----
    {
        const f32x4* np = reinterpret_cast<const f32x4*>(
            node + ((size_t)s * NA + nbase) * IND);
        #pragma unroll
        for (int i = 0; i < 16; ++i) {
            const int idx = tid + 256 * i;          // f32x4 index 0..4095
            const f32x4 v = np[idx];
            const int n  = idx >> 4;                // 16 f32x4 per 64-f32 row
            const int c8 = idx & 15;                // 8-byte half-chunk
            union { __bf16 b[4]; uint2 u; } cv;
            cv.b[0] = (__bf16)v.x; cv.b[1] = (__bf16)v.y;
            cv.b[2] = (__bf16)v.z; cv.b[3] = (__bf16)v.w;
            const int woff = n * 128 + ((c8 * 8) ^ ((n & 7) << 4));
            *reinterpret_cast<uint2*>(NodeL + woff) = cv.u;
        }
    }
    __syncthreads();

    unsigned char* tr = Tr[wv];
    const int swk = (lr & 7) << 4;                  // B-read swizzle key
    const int row2 = l >> 2;                        // readback o-row
    const int rk2 = (row2 & 7) << 4;

    for (int i = 0; i < 4; ++i) {                   // 4 n-tiles per wave
        const int ln0 = wv * 16 + i * 64;           // local n of tile
        f32x4 acc[FL];
        #pragma unroll
        for (int f = 0; f < FL; ++f) acc[f] = f32x4{0.f, 0.f, 0.f, 0.f};

        const int nrow = ln0 + lr;
        #pragma unroll
        for (int kk = 0; kk < 2; ++kk) {
            const int roff = nrow * 128 + (((kk * 4 + lg) * 16) ^ swk);
            const bf16x8 b = *reinterpret_cast<const bf16x8*>(NodeL + roff);
            #pragma unroll
            for (int f = 0; f < FL; ++f)
                acc[f] = __builtin_amdgcn_mfma_f32_16x16x32_bf16(afr[f][kk], b, acc[f], 0, 0, 0);
        }

        // scatter to transpose buf: Tr[row=o][n=lr][f] as packed bf16 pairs
        #pragma unroll
        for (int r = 0; r < 4; ++r) {
            const int row = 4 * lg + r;
            const int rk = (row & 7) << 4;
            #pragma unroll
            for (int fp = 0; fp < 6; ++fp) {
                union { __bf16 b[2]; uint32_t u; } pk;
                pk.b[0] = (__bf16)acc[2 * fp][r];
                pk.b[1] = (__bf16)acc[2 * fp + 1][r];
                *reinterpret_cast<uint32_t*>(
                    tr + row * 384 + ((lr * 24 + fp * 4) ^ rk)) = pk.u;
            }
        }
        asm volatile("s_waitcnt lgkmcnt(0)" ::: "memory");

        // coalesced readback -> global: per o-row 384 B contiguous
        __bf16* gbase = gt + ((size_t)(s * OD + o0 + row2)) * KTOT
                           + (size_t)(nbase + ln0) * FL;
        #pragma unroll
        for (int i6 = 0; i6 < 6; ++i6) {
            const int ch = (l & 3) + 4 * i6;
            const uint4 v = *reinterpret_cast<const uint4*>(
                tr + row2 * 384 + ((ch * 16) ^ rk2));
            reinterpret_cast<uint4*>(gbase)[ch] = v;
        }
        asm volatile("s_waitcnt lgkmcnt(0)" ::: "memory");   // reads done before next tile's writes
    }
}

// ---------------------------------------------------------------------------
// Kernel 2: out[s][a][o] = bond-term (base value for k_main's atomicAdd).
// ---------------------------------------------------------------------------
__global__ __launch_bounds__(256)
void k_init(const float* __restrict__ bond, const float* __restrict__ W,
            float* __restrict__ out) {
    const int bid = blockIdx.x;
    const int tid = threadIdx.x;

    __shared__ float Wb[64][25];
    for (int i = tid; i < 64 * 24; i += 256) {
        const int o = i / 24, fc = i % 24;
        const int f = fc >> 1, c = fc & 1;
        Wb[o][fc] = W[(size_t)o * (FL * WROW) + f * WROW + IND + c];
    }
    __shared__ float bl[4][24];
    if (tid < 96) {
        const int a = tid / 24, fc = tid % 24;
        bl[a][fc] = bond[(size_t)bid * 4 * (FL * 2) + a * (FL * 2) + fc];
    }
    __syncthreads();

    const int aL = tid >> 6, o = tid & 63;
    float sum = 0.f;
    #pragma unroll
    for (int f = 0; f < FL; ++f)
        sum += bl[aL][2 * f] * Wb[o][2 * f] + bl[aL][2 * f + 1] * Wb[o][2 * f + 1];
    out[((size_t)bid * 4 + aL) * OD + o] = sum;
}

// ---------------------------------------------------------------------------
// Kernel 3 (validated ~86us): pipelined LDS-staged MFMA GEMM.
// One raw s_barrier per K-step, explicit lgkmcnt(0) (no vmcnt drain), 2-deep
// register prefetch -> counted vmcnt waits, loads in flight across barriers.
// ---------------------------------------------------------------------------
struct PF { f32x4 a0, a1, a2, a3; uint4 b0, b1; };

__device__ __forceinline__ PF pf_load(const float* ap, const __bf16* bp) {
    PF p;
    p.a0 = *reinterpret_cast<const f32x4*>(ap);
    p.a1 = *reinterpret_cast<const f32x4*>(ap + 4);
    p.a2 = *reinterpret_cast<const f32x4*>(ap + 8);
    p.a3 = *reinterpret_cast<const f32x4*>(ap + 12);
    p.b0 = *reinterpret_cast<const uint4*>(bp);
    p.b1 = *reinterpret_cast<const uint4*>(bp + 8);
    return p;
}

__device__ __forceinline__ void pf_stage(unsigned char* Ab, unsigned char* Bb,
                                         const PF& p, int woff0, int woff1) {
    bf16x8 wlo, whi;
    wlo[0] = (__bf16)p.a0.x; wlo[1] = (__bf16)p.a0.y;
    wlo[2] = (__bf16)p.a0.z; wlo[3] = (__bf16)p.a0.w;
    wlo[4] = (__bf16)p.a1.x; wlo[5] = (__bf16)p.a1.y;
    wlo[6] = (__bf16)p.a1.z; wlo[7] = (__bf16)p.a1.w;
    whi[0] = (__bf16)p.a2.x; whi[1] = (__bf16)p.a2.y;
    whi[2] = (__bf16)p.a2.z; whi[3] = (__bf16)p.a2.w;
    whi[4] = (__bf16)p.a3.x; whi[5] = (__bf16)p.a3.y;
    whi[6] = (__bf16)p.a3.z; whi[7] = (__bf16)p.a3.w;
    *reinterpret_cast<bf16x8*>(Ab + woff0) = wlo;
    *reinterpret_cast<bf16x8*>(Ab + woff1) = whi;
    *reinterpret_cast<uint4*>(Bb + woff0) = p.b0;
    *reinterpret_cast<uint4*>(Bb + woff1) = p.b1;
}

__device__ __forceinline__ void mfma_phase(const unsigned char* Ab, const unsigned char* Bb,
                                           int rowA0, int rowB0, int lg, int rsw,
                                           f32x4& c00, f32x4& c01, f32x4& c10, f32x4& c11) {
    #pragma unroll
    for (int ks = 0; ks < 2; ++ks) {
        const int koff = (ks * 64 + lg * 16) ^ rsw;
        const bf16x8 am0 = *reinterpret_cast<const bf16x8*>(Ab + rowA0 + koff);
        const bf16x8 am1 = *reinterpret_cast<const bf16x8*>(Ab + rowA0 + 2048 + koff);
        const bf16x8 bn0 = *reinterpret_cast<const bf16x8*>(Bb + rowB0 + koff);
        const bf16x8 bn1 = *reinterpret_cast<const bf16x8*>(Bb + rowB0 + 2048 + koff);
        c00 = __builtin_amdgcn_mfma_f32_16x16x32_bf16(am0, bn0, c00, 0, 0, 0);
        c01 = __builtin_amdgcn_mfma_f32_16x16x32_bf16(am0, bn1, c01, 0, 0, 0);
        c10 = __builtin_amdgcn_mfma_f32_16x16x32_bf16(am1, bn0, c10, 0, 0, 0);
        c11 = __builtin_amdgcn_mfma_f32_16x16x32_bf16(am1, bn1, c11, 0, 0, 0);
    }
}

__global__ __launch_bounds__(256, 4)
void k_main(const float* __restrict__ conn, const __bf16* __restrict__ gt,
            float* __restrict__ out) {
    const int bid = blockIdx.x;
    const int s  = bid & 31;
    const int x  = bid >> 5;
    const int at = x >> 2;            // 0..7
    const int kq = x & 3;             // 0..3
    const int a0 = at << 6;
    const int k00 = kq * (KTOT / 4);  // 1536-elem K slice, 24 steps of 64
    const int tid = threadIdx.x;
    const int w  = tid >> 6, l = tid & 63;
    const int lr = l & 15, lg = l >> 4;
    const int m0 = (w >> 1) << 5;
    const int n0 = (w & 1) << 5;

    __shared__ __align__(16) unsigned char Al0[8192];
    __shared__ __align__(16) unsigned char Al1[8192];
    __shared__ __align__(16) unsigned char Bl0[8192];
    __shared__ __align__(16) unsigned char Bl1[8192];

    const int srow = tid >> 2;
    const int scol = tid & 3;
    const float*  aG = conn + ((size_t)s * NA + a0 + srow) * KTOT + k00 + scol * 16;
    const __bf16* bG = gt   + ((size_t)s * OD + srow)      * KTOT + k00 + scol * 16;
    const int wsw   = (srow & 7) << 4;
    const int woff0 = srow * 128 + ((scol * 32) ^ wsw);
    const int woff1 = srow * 128 + ((scol * 32 + 16) ^ wsw);

    f32x4 acc00 = {0.f,0.f,0.f,0.f}, acc01 = {0.f,0.f,0.f,0.f};
    f32x4 acc10 = {0.f,0.f,0.f,0.f}, acc11 = {0.f,0.f,0.f,0.f};

    const int rsw = (lr & 7) << 4;
    const int rowA0 = (m0 + lr) * 128;
    const int rowB0 = (n0 + lr) * 128;

    PF P0 = pf_load(aG, bG);
    PF P1 = pf_load(aG + 64, bG + 64);

    #pragma unroll 1
    for (int t = 0; t < 24; t += 2) {
        // ---- even step: buffer 0 ----
        pf_stage(Al0, Bl0, P0, woff0, woff1);          // waits vmcnt(6): P1 in flight
        if (t + 2 < 24) P0 = pf_load(aG + (t + 2) * 64, bG + (t + 2) * 64);
        asm volatile("s_waitcnt lgkmcnt(0)" ::: "memory");
        __builtin_amdgcn_s_barrier();
        mfma_phase(Al0, Bl0, rowA0, rowB0, lg, rsw, acc00, acc01, acc10, acc11);

        // ---- odd step: buffer 1 ----
        pf_stage(Al1, Bl1, P1, woff0, woff1);
        if (t + 3 < 24) P1 = pf_load(aG + (t + 3) * 64, bG + (t + 3) * 64);
        asm volatile("s_waitcnt lgkmcnt(0)" ::: "memory");
        __builtin_amdgcn_s_barrier();
        mfma_phase(Al1, Bl1, rowA0, rowB0, lg, rsw, acc00, acc01, acc10, acc11);
    }

    // epilogue: atomic accumulate partials. D: col=lane&15, row=4*(lane>>4)+r
    float* ob = out + ((size_t)s * NA + a0 + m0 + lg * 4) * OD + n0 + lr;
    #pragma unroll
    for (int r = 0; r < 4; ++r) {
        atomicAdd(ob + (size_t)(r) * OD,            acc00[r]);
        atomicAdd(ob + (size_t)(r) * OD + 16,       acc01[r]);
        atomicAdd(ob + (size_t)(16 + r) * OD,       acc10[r]);
        atomicAdd(ob + (size_t)(16 + r) * OD + 16,  acc11[r]);
    }
}

extern "C" void kernel_launch(void* const* d_in, const int* in_sizes, int n_in,
                              void* d_out, int out_size, void* d_ws, size_t ws_size,
                              hipStream_t stream) {
    const float* node = (const float*)d_in[0];
    const float* conn = (const float*)d_in[1];
    const float* bond = (const float*)d_in[2];
    const float* W    = (const float*)d_in[3];
    float* out = (float*)d_out;
    __bf16* gt = (__bf16*)d_ws;    // 32*64*6144 bf16 = 25.2 MB

    k_prep<<<dim3(256), dim3(256), 0, stream>>>(node, W, gt);
    k_init<<<dim3(NS * NA / 4), dim3(256), 0, stream>>>(bond, W, out);
    k_main<<<dim3(NS * 32), dim3(256), 0, stream>>>(conn, gt, out);
}